// Round 2
// baseline (336.150 us; speedup 1.0000x reference)
//
#include <hip/hip_runtime.h>
#include <math.h>

#define NXC 256
#define NQC 256
#define NUC 64
#define NHC 512
#define BR  32768
#define EPSC 1e-3f
#define NAUG 768

typedef _Float16 h2_t __attribute__((ext_vector_type(2)));
typedef _Float16 f16x8 __attribute__((ext_vector_type(8)));
typedef float f32x4 __attribute__((ext_vector_type(4)));
union h2u { h2_t h; unsigned int u; };

__device__ __forceinline__ h2_t pk_f16(float a, float b) {
#if __has_builtin(__builtin_amdgcn_cvt_pkrtz)
  return __builtin_bit_cast(h2_t, __builtin_amdgcn_cvt_pkrtz(a, b));
#else
  h2_t r; r.x = (_Float16)a; r.y = (_Float16)b; return r;
#endif
}
__device__ __forceinline__ unsigned int pk_bits(float a, float b) { h2u x; x.h = pk_f16(a, b); return x.u; }
__device__ __forceinline__ h2_t b2h(unsigned int u) { h2u x; x.u = u; return x.h; }
__device__ __forceinline__ unsigned int h2b(h2_t v) { h2u x; x.h = v; return x.u; }

__device__ __forceinline__ float fdot2f(h2_t a, h2_t b, float c) {
#if __has_builtin(__builtin_amdgcn_fdot2)
  return __builtin_amdgcn_fdot2(a, b, c, false);
#else
  return c + (float)a.x * (float)b.x + (float)a.y * (float)b.y;
#endif
}

__device__ __forceinline__ float fast_tanh(float x) {
  float ax = fabsf(x);
  float e  = __expf(-2.0f * ax);
  float r  = __fdividef(1.0f - e, 1.0f + e);
  return copysignf(r, x);
}

__device__ __forceinline__ float fast_rcp(float x) {
#if __has_builtin(__builtin_amdgcn_rcpf)
  return __builtin_amdgcn_rcpf(x);
#else
  return 1.0f / x;
#endif
}

// in-register GJ inversion of a 32x32 block, one row per lane (lanes 0..31; 32..63
// mirror harmlessly). Verified rounds 9/14/15; rcp swapped for v_rcp_f32 (err ~2^-22,
// negligible before the f16 downcast of A/B1).
__device__ __forceinline__ void inv32_wave(float r[32], int ii) {
#pragma unroll
  for (int k = 0; k < 32; ++k) {
    float rk[32];
#pragma unroll
    for (int j = 0; j < 32; ++j) rk[j] = __shfl(r[j], k);
    float d = fast_rcp(rk[k]);
    float fik = r[k];
    if (ii == k) {
#pragma unroll
      for (int j = 0; j < 32; ++j) r[j] = (j == k) ? d : rk[j] * d;
    } else {
#pragma unroll
      for (int j = 0; j < 32; ++j) r[j] = (j == k) ? (-fik * d) : (r[j] - fik * (d * rk[j]));
    }
  }
}

// ---------------- H and P SYRKs via f16 MFMA, one launch ----------------
// P lands in the left 256 cols of the augmented buffer N = [P | Y | Z] (pitch 768).
__global__ __launch_bounds__(256) void syrk_mfma_kernel(const float* __restrict__ Xin,
                                                        const float* __restrict__ Pstar,
                                                        float* __restrict__ Hm,
                                                        float* __restrict__ Naug) {
  __shared__ _Float16 Alds[128][72];
  __shared__ _Float16 Blds[64][72];
  const int b = blockIdx.x, t = threadIdx.x;
  const float* src; float* dst; int n, K; float scale; int rowbase, colbase;
  if (b < 32) { src = Xin;   dst = Hm;   n = NHC;  K = NHC; scale = 1.0f; rowbase = (b >> 3) * 128; colbase = (b & 7) * 64; }
  else { int b2 = b - 32; src = Pstar; dst = Naug; n = NAUG; K = NXC; scale = 0.5f; rowbase = (b2 >> 2) * 128; colbase = (b2 & 3) * 64; }
  const int r_a = t >> 1, h_a = t & 1;
  const int r_b = t >> 2, q_b = t & 3;
  const int lane = t & 63, wv = t >> 6;
  const int wm = wv >> 1, wn = wv & 1;
  const int l15 = lane & 15, l4 = lane >> 4;
  f32x4 acc[4][2] = {};
  for (int k0 = 0; k0 < K; k0 += 64) {
    uint4 av[4], bvv[2];
    {
      const float* p = src + (size_t)(rowbase + r_a) * K + k0 + h_a * 32;
#pragma unroll
      for (int m = 0; m < 4; m++) {
        float4 x0 = *(const float4*)(p + m * 8);
        float4 x1 = *(const float4*)(p + m * 8 + 4);
        uint4 pk;
        pk.x = pk_bits(x0.x, x0.y); pk.y = pk_bits(x0.z, x0.w);
        pk.z = pk_bits(x1.x, x1.y); pk.w = pk_bits(x1.z, x1.w);
        av[m] = pk;
      }
    }
    {
      const float* p = src + (size_t)(colbase + r_b) * K + k0 + q_b * 16;
      float4 x0 = *(const float4*)p,       x1 = *(const float4*)(p + 4);
      float4 x2 = *(const float4*)(p + 8), x3 = *(const float4*)(p + 12);
      bvv[0].x = pk_bits(x0.x, x0.y); bvv[0].y = pk_bits(x0.z, x0.w);
      bvv[0].z = pk_bits(x1.x, x1.y); bvv[0].w = pk_bits(x1.z, x1.w);
      bvv[1].x = pk_bits(x2.x, x2.y); bvv[1].y = pk_bits(x2.z, x2.w);
      bvv[1].z = pk_bits(x3.x, x3.y); bvv[1].w = pk_bits(x3.z, x3.w);
    }
    __syncthreads();
#pragma unroll
    for (int m = 0; m < 4; m++) *(uint4*)&Alds[r_a][h_a * 32 + m * 8] = av[m];
    *(uint4*)&Blds[r_b][q_b * 16]     = bvv[0];
    *(uint4*)&Blds[r_b][q_b * 16 + 8] = bvv[1];
    __syncthreads();
#pragma unroll
    for (int ks = 0; ks < 2; ks++) {
      f16x8 af[4], bf[2];
#pragma unroll
      for (int fm = 0; fm < 4; fm++)
        af[fm] = *(const f16x8*)&Alds[wm * 64 + fm * 16 + l15][ks * 32 + l4 * 8];
#pragma unroll
      for (int fn = 0; fn < 2; fn++)
        bf[fn] = *(const f16x8*)&Blds[wn * 32 + fn * 16 + l15][ks * 32 + l4 * 8];
#pragma unroll
      for (int fm = 0; fm < 4; fm++)
#pragma unroll
        for (int fn = 0; fn < 2; fn++)
          acc[fm][fn] = __builtin_amdgcn_mfma_f32_16x16x32_f16(af[fm], bf[fn], acc[fm][fn], 0, 0, 0);
    }
  }
#pragma unroll
  for (int fm = 0; fm < 4; fm++)
#pragma unroll
    for (int fn = 0; fn < 2; fn++) {
      int col = colbase + wn * 32 + fn * 16 + l15;
      f32x4 a = acc[fm][fn];
#pragma unroll
      for (int reg = 0; reg < 4; reg++) {
        int row = rowbase + wm * 64 + fm * 16 + l4 * 4 + reg;
        float val = scale * a[reg] + ((row == col) ? EPSC : 0.f);
        dst[(size_t)row * n + col] = val;
      }
    }
}

// ---------------- derived small matrices (+ f16 weights + packed D11 pairs) --------
// Y, Z written straight into the augmented buffer N = [P | Y | Z].
__global__ __launch_bounds__(256) void derive_kernel(const float* __restrict__ H,
                                                     const float* __restrict__ Y1,
                                                     const float* __restrict__ Chi,
                                                     const float* __restrict__ D12,
                                                     const float* __restrict__ B2,
                                                     float* __restrict__ Naug,
                                                     unsigned int* __restrict__ dpk_g,
                                                     _Float16* __restrict__ C1h,
                                                     _Float16* __restrict__ D12h,
                                                     _Float16* __restrict__ B2h) {
  int i = blockIdx.x, j = threadIdx.x;
  float li = 2.0f / H[(size_t)(NXC + i) * NHC + NXC + i];
  Naug[(size_t)i * NAUG + NXC + j]     = -0.5f * (H[(size_t)i * NHC + j] + Y1[i * NXC + j] - Y1[j * NXC + i]);
  C1h[i * NXC + j] = (_Float16)(li * Chi[j * NQC + i]);
  Naug[(size_t)i * NAUG + 2 * NXC + j] = -H[(size_t)i * NHC + NXC + j] - Chi[i * NQC + j];
  float dv = (j < i) ? (-li * H[(size_t)(NXC + i) * NHC + NXC + j]) : 0.f;
  float dhi = __shfl_xor(dv, 1);
  if ((j & 1) == 0) dpk_g[(size_t)(j >> 1) * NXC + i] = pk_bits(dv, dhi);
  if (j < NUC) {
    D12h[i * NUC + j] = (_Float16)D12[i * NUC + j];
    B2h[i * NUC + j]  = (_Float16)B2[i * NUC + j];
  }
}

// ---------------- fused blocked GJ step on augmented [P | Y | Z] ----------------
// One launch per 32-wide pivot block (8 total). Ping-pong Nin -> Nout so no
// inter-block sync is needed: every block reads only stale values, writes only its
// own 8 rows. Every block redundantly inverts the 32x32 diagonal block in registers
// (latency-bound, parallel across blocks so redundancy is free). Columns < k0+32
// are dead (never read again) and skipped. Last step emits A,B1 in f16 directly.
__global__ __launch_bounds__(256) void gjstep_kernel(const float* __restrict__ Nin,
                                                     float* __restrict__ Nout,
                                                     _Float16* __restrict__ Ah,
                                                     _Float16* __restrict__ B1h,
                                                     int k0) {
  __shared__ float Dl[32][33];
  __shared__ float cfl[8][33];
  const int t = threadIdx.x;
  const int row0 = blockIdx.x * 8;
  const bool last = (k0 + 32 == NXC);
  // wave 0: invert diagonal block
  if (t < 64) {
    const int ii = t & 31;
    float r[32];
#pragma unroll
    for (int j = 0; j < 32; ++j) r[j] = Nin[(size_t)(k0 + ii) * NAUG + k0 + j];
    inv32_wave(r, ii);
    if (t < 32) {
#pragma unroll
      for (int j = 0; j < 32; ++j) Dl[ii][j] = r[j];
    }
  }
  __syncthreads();
  // coef[rr][s]: Dinv row (pivot rows) or -f@Dinv (other rows); thread (rr=t>>5, s=t&31)
  {
    const int rr = t >> 5, s = t & 31;
    const int i = row0 + rr;
    float c;
    if (i >= k0 && i < k0 + 32) {
      c = Dl[i - k0][s];
    } else {
      float g = 0.f;
#pragma unroll
      for (int q = 0; q < 32; ++q) g = fmaf(Nin[(size_t)i * NAUG + k0 + q], Dl[q][s], g);
      c = -g;
    }
    cfl[rr][s] = c;
  }
  __syncthreads();
  // row update: row_out = base + coef @ panel_old over active columns [k0+32, 768)
  const int rr = t >> 5;
  const int i = row0 + rr;
  const bool piv = (i >= k0 && i < k0 + 32);
  float cf[32];
#pragma unroll
  for (int s = 0; s < 32; ++s) cf[s] = cfl[rr][s];
  const int c40 = (k0 + 32) >> 2;
  for (int c4 = c40 + (t & 31); c4 < (NAUG >> 2); c4 += 32) {
    float4 acc;
    if (piv) { acc.x = 0.f; acc.y = 0.f; acc.z = 0.f; acc.w = 0.f; }
    else     { acc = *(const float4*)&Nin[(size_t)i * NAUG + c4 * 4]; }
#pragma unroll
    for (int s = 0; s < 32; ++s) {
      float4 pv = *(const float4*)&Nin[(size_t)(k0 + s) * NAUG + c4 * 4];
      acc.x = fmaf(cf[s], pv.x, acc.x);
      acc.y = fmaf(cf[s], pv.y, acc.y);
      acc.z = fmaf(cf[s], pv.z, acc.z);
      acc.w = fmaf(cf[s], pv.w, acc.w);
    }
    if (!last) {
      *(float4*)&Nout[(size_t)i * NAUG + c4 * 4] = acc;
    } else {
      int cc = c4 * 4 - NXC;  // 0..511 within [A | B1]
      h2_t h0, h1;
      h0.x = (_Float16)acc.x; h0.y = (_Float16)acc.y;
      h1.x = (_Float16)acc.z; h1.y = (_Float16)acc.w;
      uint2 o; o.x = h2b(h0); o.y = h2b(h1);
      if (cc < NXC) *(uint2*)&Ah[(size_t)i * NXC + cc]          = o;
      else          *(uint2*)&B1h[(size_t)i * NXC + (cc - NXC)] = o;
    }
  }
}

// ---------------- MFMA GEMM, BN=128 (halved column-block refetch) ----------------
// BM=128, BN=128, BK=64; 4 waves 2x2, wave tile 64x64 = 4x4 frags of 16x16.
__device__ __forceinline__ void mm_term(const void* __restrict__ Xv,
                                        const _Float16* __restrict__ W,
                                        int K, int ld, int isf16,
                                        int rowbase, int colbase, int t,
                                        _Float16 (*Alds)[72], _Float16 (*Blds)[72],
                                        f32x4 (&acc)[4][4]) {
  const int r_a = t >> 1, h_a = t & 1;
  const int lane = t & 63, wv = t >> 6;
  const int wm = wv >> 1, wn = wv & 1;
  const int l15 = lane & 15, l4 = lane >> 4;
  for (int k0 = 0; k0 < K; k0 += 64) {
    uint4 av[4], bvv[4];
    if (isf16) {
      const _Float16* p = (const _Float16*)Xv + (size_t)(rowbase + r_a) * ld + k0 + h_a * 32;
#pragma unroll
      for (int m = 0; m < 4; m++) av[m] = *(const uint4*)(p + m * 8);
    } else {
      const float* p = (const float*)Xv + (size_t)(rowbase + r_a) * ld + k0 + h_a * 32;
#pragma unroll
      for (int m = 0; m < 4; m++) {
        float4 x0 = *(const float4*)(p + m * 8);
        float4 x1 = *(const float4*)(p + m * 8 + 4);
        uint4 pk;
        pk.x = pk_bits(x0.x, x0.y); pk.y = pk_bits(x0.z, x0.w);
        pk.z = pk_bits(x1.x, x1.y); pk.w = pk_bits(x1.z, x1.w);
        av[m] = pk;
      }
    }
    {
      const _Float16* p = W + (size_t)(colbase + r_a) * K + k0 + h_a * 32;
#pragma unroll
      for (int m = 0; m < 4; m++) bvv[m] = *(const uint4*)(p + m * 8);
    }
    __syncthreads();
#pragma unroll
    for (int m = 0; m < 4; m++) *(uint4*)&Alds[r_a][h_a * 32 + m * 8] = av[m];
#pragma unroll
    for (int m = 0; m < 4; m++) *(uint4*)&Blds[r_a][h_a * 32 + m * 8] = bvv[m];
    __syncthreads();
#pragma unroll
    for (int ks = 0; ks < 2; ks++) {
      f16x8 af[4], bf[4];
#pragma unroll
      for (int fm = 0; fm < 4; fm++)
        af[fm] = *(const f16x8*)&Alds[wm * 64 + fm * 16 + l15][ks * 32 + l4 * 8];
#pragma unroll
      for (int fn = 0; fn < 4; fn++)
        bf[fn] = *(const f16x8*)&Blds[wn * 64 + fn * 16 + l15][ks * 32 + l4 * 8];
#pragma unroll
      for (int fm = 0; fm < 4; fm++)
#pragma unroll
        for (int fn = 0; fn < 4; fn++)
          acc[fm][fn] = __builtin_amdgcn_mfma_f32_16x16x32_f16(af[fm], bf[fn], acc[fm][fn], 0, 0, 0);
    }
  }
}

__global__ __launch_bounds__(256) void mfma_mm_kernel(
    const void* __restrict__ X1, const _Float16* __restrict__ W1, int K1, int ld1, int f1,
    const void* __restrict__ X2, const _Float16* __restrict__ W2, int K2, int ld2, int f2,
    const void* __restrict__ X3, const _Float16* __restrict__ W3, int K3, int ld3, int f3,
    const float* __restrict__ bias, void* __restrict__ out, int N, int of16) {
  __shared__ _Float16 Alds[128][72];
  __shared__ _Float16 Blds[128][72];
  int t = threadIdx.x;
  int rowbase = blockIdx.y * 128, colbase = blockIdx.x * 128;
  f32x4 acc[4][4] = {};
  mm_term(X1, W1, K1, ld1, f1, rowbase, colbase, t, Alds, Blds, acc);
  if (K2) mm_term(X2, W2, K2, ld2, f2, rowbase, colbase, t, Alds, Blds, acc);
  if (K3) mm_term(X3, W3, K3, ld3, f3, rowbase, colbase, t, Alds, Blds, acc);
  const int lane = t & 63, wv = t >> 6;
  const int wm = wv >> 1, wn = wv & 1;
  const int l15 = lane & 15, l4 = lane >> 4;
#pragma unroll
  for (int fm = 0; fm < 4; fm++)
#pragma unroll
    for (int fn = 0; fn < 4; fn++) {
      int col = colbase + wn * 64 + fn * 16 + l15;
      float b = bias[col];
      f32x4 a = acc[fm][fn];
#pragma unroll
      for (int reg = 0; reg < 4; reg++) {
        int row = rowbase + wm * 64 + fm * 16 + l4 * 4 + reg;
        if (of16) ((_Float16*)out)[(size_t)row * N + col] = (_Float16)(a[reg] + b);
        else      ((float*)out)[(size_t)row * N + col]    = a[reg] + b;
      }
    }
}

// ---------------- w recurrence v10: MFMA cross phase (round-16, unchanged) --------
__global__ __launch_bounds__(256) void wrec_kernel(float* __restrict__ vw,
                                                   const unsigned int* __restrict__ dpk_g) {
  __shared__ unsigned int wlds[64 * 132];
  __shared__ unsigned int dpkT[32 * 116];
  __shared__ unsigned int tript[32 * 16];
  __shared__ float vbuf[64 * 36];
  const int t = threadIdx.x;
  const int r = t >> 2, s = t & 3;
  const int lane = t & 63, w = t >> 6;
  const int l15 = lane & 15, l4 = lane >> 4;
  const size_t rowbase = (size_t)blockIdx.x * 64;
  float* vrow  = vw + (rowbase + r) * NQC;
  const float* vblock = vw + rowbase * NQC;
  unsigned int* wout = (unsigned int*)vrow;
  const _Float16* wl16 = (const _Float16*)wlds;
  h2_t wpk[16];
#pragma unroll
  for (int p = 0; p < 16; ++p) wpk[p] = pk_f16(0.f, 0.f);

  for (int kb = 0; kb < 8; ++kb) {
    const int i0 = kb * 32;
    for (int idx = t; idx < (i0 >> 1) * 32; idx += 256) {
      int cc = idx & 31, jp = idx >> 5;
      dpkT[cc * 116 + jp] = dpk_g[(size_t)jp * NXC + i0 + cc];
    }
    if (t < 128) {
      int jp = t >> 3, iq = t & 7;
      uint4 d4 = *(const uint4*)&dpk_g[(size_t)(i0 / 2 + jp) * NXC + i0 + iq * 4];
      tript[(iq * 4 + 0) * 16 + jp] = d4.x;
      tript[(iq * 4 + 1) * 16 + jp] = d4.y;
      tript[(iq * 4 + 2) * 16 + jp] = d4.z;
      tript[(iq * 4 + 3) * 16 + jp] = d4.w;
    }
    f32x4 acc0, acc1;
#pragma unroll
    for (int reg = 0; reg < 4; ++reg) {
      int rowm = w * 16 + l4 * 4 + reg;
      acc0[reg] = vblock[(size_t)rowm * NQC + i0 + l15];
      acc1[reg] = vblock[(size_t)rowm * NQC + i0 + 16 + l15];
    }
    __syncthreads();

    for (int ks = 0; ks < kb; ++ks) {
      f16x8 af = *(const f16x8*)&wl16[(size_t)(w * 16 + l15) * 264 + ks * 32 + l4 * 8];
      uint4 b0 = *(const uint4*)&dpkT[(l15) * 116 + ks * 16 + l4 * 4];
      uint4 b1 = *(const uint4*)&dpkT[(16 + l15) * 116 + ks * 16 + l4 * 4];
      acc0 = __builtin_amdgcn_mfma_f32_16x16x32_f16(af, __builtin_bit_cast(f16x8, b0), acc0, 0, 0, 0);
      acc1 = __builtin_amdgcn_mfma_f32_16x16x32_f16(af, __builtin_bit_cast(f16x8, b1), acc1, 0, 0, 0);
    }

#pragma unroll
    for (int reg = 0; reg < 4; ++reg) {
      int rowm = w * 16 + l4 * 4 + reg;
      vbuf[rowm * 36 + l15]      = acc0[reg];
      vbuf[rowm * 36 + 16 + l15] = acc1[reg];
    }

    float wprev = 0.f;
#pragma unroll
    for (int i = 0; i < 32; ++i) {
      const int npairs = (i + 1) >> 1;
      const int nq = (npairs + 3) >> 2;
      float td0 = 0.f, td1 = 0.f;
#pragma unroll
      for (int q = 0; q < nq; ++q) {
        uint4 tq = *(const uint4*)&tript[i * 16 + q * 4];
        td0 = fdot2f(wpk[q * 4 + 0], b2h(tq.x), td0);
        td1 = fdot2f(wpk[q * 4 + 1], b2h(tq.y), td1);
        td0 = fdot2f(wpk[q * 4 + 2], b2h(tq.z), td0);
        td1 = fdot2f(wpk[q * 4 + 3], b2h(tq.w), td1);
      }
      float vi = vbuf[r * 36 + i];
      float wi = fast_tanh(vi + td0 + td1);
      if ((i & 1) == 0) { wprev = wi; wpk[i >> 1] = pk_f16(wi, 0.f); }
      else              { wpk[i >> 1] = pk_f16(wprev, wi); }
    }

    {
      uint4 o;
      o.x = h2b(wpk[s * 4 + 0]); o.y = h2b(wpk[s * 4 + 1]);
      o.z = h2b(wpk[s * 4 + 2]); o.w = h2b(wpk[s * 4 + 3]);
      *(uint4*)&wlds[r * 132 + kb * 16 + s * 4] = o;
      *(uint4*)&wout[kb * 16 + s * 4] = o;
    }
    __syncthreads();
  }
}

extern "C" void kernel_launch(void* const* d_in, const int* in_sizes, int n_in,
                              void* d_out, int out_size, void* d_ws, size_t ws_size,
                              hipStream_t stream) {
  (void)in_sizes; (void)n_in; (void)out_size; (void)ws_size;
  const float* xi    = (const float*)d_in[1];
  const float* u     = (const float*)d_in[2];
  const float* Pstar = (const float*)d_in[3];
  const float* Chi   = (const float*)d_in[4];
  const float* Y1    = (const float*)d_in[5];
  const float* B2    = (const float*)d_in[6];
  const float* D12   = (const float*)d_in[7];
  const float* Xin   = (const float*)d_in[8];
  const float* bx    = (const float*)d_in[9];
  const float* bv    = (const float*)d_in[10];
  float* out = (float*)d_out;

  float* ws    = (float*)d_ws;
  float* vw    = ws;                            // B*NQ fp32 v_base; w f16 packed in place
  float* Hm    = vw + (size_t)BR * NQC;         // 512*512
  float* NA    = Hm + (size_t)NHC * NHC;        // 256*768 augmented [P|Y|Z], ping
  float* NB    = NA + (size_t)NXC * NAUG;       // 256*768 pong
  unsigned int* dpkg = (unsigned int*)(NB + (size_t)NXC * NAUG);   // 128*256 u32
  _Float16* C1h  = (_Float16*)(dpkg + 128 * 256);
  _Float16* D12h = C1h + (size_t)NQC * NXC;
  _Float16* Ah   = D12h + (size_t)NQC * NUC;
  _Float16* B1h  = Ah + (size_t)NXC * NXC;
  _Float16* B2h  = B1h + (size_t)NXC * NQC;

  // setup: both SYRKs (MFMA; P lands in NA left block), derive (Y,Z into NA right)
  syrk_mfma_kernel<<<40, 256, 0, stream>>>(Xin, Pstar, Hm, NA);
  derive_kernel<<<NXC, NXC, 0, stream>>>(Hm, Y1, Chi, D12, B2, NA, dpkg, C1h, D12h, B2h);

  // blocked Gauss-Jordan on augmented [P|Y|Z], ping-pong, 8 launches.
  // Last step writes Ah = f16(P^-1 Y), B1h = f16(P^-1 Z) directly.
  for (int kb = 0; kb < 8; ++kb) {
    const float* Nin = (kb & 1) ? NB : NA;
    float*      Nout = (kb & 1) ? NA : NB;
    gjstep_kernel<<<32, 256, 0, stream>>>(Nin, Nout, Ah, B1h, kb * 32);
  }

  // v_base = xi@C1^T + u@D12^T + bv   (MFMA f16, fp32 output, BN=128)
  mfma_mm_kernel<<<dim3(NQC / 128, BR / 128), 256, 0, stream>>>(
      xi, C1h, NXC, NXC, 0,
      u,  D12h, NUC, NUC, 0,
      nullptr, nullptr, 0, 0, 0,
      bv, vw, NQC, 0);

  // w recurrence: 64 rows/block, MFMA cross + R7 tri
  wrec_kernel<<<BR / 64, 256, 0, stream>>>(vw, dpkg);

  // xi_dot = xi@A^T + w@B1^T + u@B2^T + bx   (w term f16 in-place rows, ld=512, BN=128)
  mfma_mm_kernel<<<dim3(NXC / 128, BR / 128), 256, 0, stream>>>(
      xi, Ah, NXC, NXC, 0,
      vw, B1h, NXC, 512, 1,
      u,  B2h, NUC, NUC, 0,
      bx, out, NXC, 0);
}